// Round 8
// baseline (193.127 us; speedup 1.0000x reference)
//
#include <hip/hip_runtime.h>
#include <hip/hip_bf16.h>
#include <math.h>

#define B_ 32
#define T_ 128
#define C_ 64
#define E_ 8
#define HID_ 32

__device__ __forceinline__ float sigmoidf_(float x) { return 1.0f / (1.0f + __expf(-x)); }
__device__ __forceinline__ float tanhf_(float x) {
    float xc = fminf(fmaxf(x, -15.0f), 15.0f);
    float e = __expf(2.0f * xc);
    return (e - 1.0f) / (e + 1.0f);
}

// ---------------------------------------------------------------------------
// Kernel A: per-batch GRU + out0 (f32). grid = B, block = 512 (64 chains x 8)
// xp = x @ W_in^T + b_in  (einsum 'btc,dc->btd', literal reading)
// ---------------------------------------------------------------------------
__global__ __launch_bounds__(512) void k_gru_out(
    const float* __restrict__ x, const float* __restrict__ W_in, const float* __restrict__ b_in,
    const float* __restrict__ W_ih, const float* __restrict__ W_hh,
    const float* __restrict__ b_ih, const float* __restrict__ b_hh,
    const float* __restrict__ W_out, const float* __restrict__ b_out,
    float* __restrict__ out0)
{
    const int b = blockIdx.x;
    const int tid = threadIdx.x;
    const int ci = tid >> 3;        // channel c (the chain)
    const int e = tid & 7;          // hidden unit lane

    __shared__ float xc[C_][T_ + 1];
    __shared__ float hf[C_ * E_];

    // xcol: chain ci, lane e computes t in [e*16, e*16+16)
    // xp[b,t,ci] = b_in[ci] + sum_k x[b,t,k] * W_in[ci, k]   ('dc')
    const float bi = b_in[ci];
    const float* wrow = W_in + ci * C_;
    for (int tt = 0; tt < 16; ++tt) {
        const int t = e * 16 + tt;
        const float4* xr = (const float4*)(x + (b * T_ + t) * C_);
        const float4* wv4 = (const float4*)wrow;
        float a = bi;
#pragma unroll
        for (int k4 = 0; k4 < 16; ++k4) {
            float4 xv = xr[k4];
            float4 wv = wv4[k4];
            a = fmaf(xv.x, wv.x, a); a = fmaf(xv.y, wv.y, a);
            a = fmaf(xv.z, wv.z, a); a = fmaf(xv.w, wv.w, a);
        }
        xc[ci][t] = a;
    }
    __syncthreads();

    // GRU: 8 lanes per chain, shfl width 8
    float wr[E_], wz[E_], wn[E_];
#pragma unroll
    for (int j = 0; j < E_; ++j) {
        wr[j] = W_hh[(ci * 24 + 0 * E_ + e) * E_ + j];
        wz[j] = W_hh[(ci * 24 + 1 * E_ + e) * E_ + j];
        wn[j] = W_hh[(ci * 24 + 2 * E_ + e) * E_ + j];
    }
    const float wir = W_ih[ci * 24 + e], wiz = W_ih[ci * 24 + E_ + e], win = W_ih[ci * 24 + 2 * E_ + e];
    const float bir = b_ih[ci * 24 + e], biz = b_ih[ci * 24 + E_ + e], bin_ = b_ih[ci * 24 + 2 * E_ + e];
    const float bhr = b_hh[ci * 24 + e], bhz = b_hh[ci * 24 + E_ + e], bhn = b_hh[ci * 24 + 2 * E_ + e];

    float h = 0.0f;
    for (int t = 0; t < T_; ++t) {
        float xv = xc[ci][t];
        float gr = fmaf(xv, wir, bir) + bhr;
        float gz = fmaf(xv, wiz, biz) + bhz;
        float gn = fmaf(xv, win, bin_);
        float hn = bhn;
#pragma unroll
        for (int j = 0; j < E_; ++j) {
            float hj = __shfl(h, j, E_);
            gr = fmaf(hj, wr[j], gr);
            gz = fmaf(hj, wz[j], gz);
            hn = fmaf(hj, wn[j], hn);
        }
        float r = sigmoidf_(gr);
        float z = sigmoidf_(gz);
        float nn = tanhf_(fmaf(r, hn, gn));
        h = (1.0f - z) * nn + z * h;
    }
    hf[ci * E_ + e] = h;
    __syncthreads();

    if (tid < HID_) {
        float a = b_out[tid];
        const float* wo = W_out + tid * (C_ * E_);
        for (int k = 0; k < C_ * E_; ++k) a = fmaf(hf[k], wo[k], a);
        out0[b * HID_ + tid] = a;
    }
}

// ---------------------------------------------------------------------------
// Kernel B: per-chain xp + GRU + attention -> feat_imp, tsf_imp (f32).
// grid = B*C, block = 128.
// ---------------------------------------------------------------------------
__global__ __launch_bounds__(128) void k_attn_f(
    const float* __restrict__ x, const float* __restrict__ W_in, const float* __restrict__ b_in,
    const float* __restrict__ W_ih, const float* __restrict__ W_hh,
    const float* __restrict__ b_ih, const float* __restrict__ b_hh,
    const float* __restrict__ W_qkv, const float* __restrict__ b_qkv,
    const float* __restrict__ W_o, const float* __restrict__ b_o,
    float* __restrict__ feat_imp, float* __restrict__ tsf_imp)
{
    const int bc = blockIdx.x;
    const int b = bc >> 6, c = bc & 63;
    const int tid = threadIdx.x;

    __shared__ __align__(16) float ks[T_][E_];
    __shared__ __align__(16) float vs[T_][E_];
    __shared__ __align__(16) float hsl[T_][E_];
    __shared__ float xcol[T_];
    __shared__ float win_c[C_];

    if (tid < C_) win_c[tid] = W_in[c * C_ + tid];   // row c of W_in ('dc')
    __syncthreads();

    {
        float a = b_in[c];
        const float* xr = x + (b * T_ + tid) * C_;
        for (int k = 0; k < C_; ++k) a = fmaf(xr[k], win_c[k], a);
        xcol[tid] = a;
    }
    __syncthreads();

    if (tid < E_) {
        const int e = tid;
        float wr[E_], wz[E_], wn[E_];
#pragma unroll
        for (int j = 0; j < E_; ++j) {
            wr[j] = W_hh[(c * 24 + 0 * E_ + e) * E_ + j];
            wz[j] = W_hh[(c * 24 + 1 * E_ + e) * E_ + j];
            wn[j] = W_hh[(c * 24 + 2 * E_ + e) * E_ + j];
        }
        const float wir = W_ih[c * 24 + e], wiz = W_ih[c * 24 + E_ + e], win = W_ih[c * 24 + 2 * E_ + e];
        const float bir = b_ih[c * 24 + e], biz = b_ih[c * 24 + E_ + e], bin_ = b_ih[c * 24 + 2 * E_ + e];
        const float bhr = b_hh[c * 24 + e], bhz = b_hh[c * 24 + E_ + e], bhn = b_hh[c * 24 + 2 * E_ + e];

        float h = 0.0f;
        for (int t = 0; t < T_; ++t) {
            float xv = xcol[t];
            float gr = fmaf(xv, wir, bir) + bhr;
            float gz = fmaf(xv, wiz, biz) + bhz;
            float gn = fmaf(xv, win, bin_);
            float hn = bhn;
#pragma unroll
            for (int j = 0; j < E_; ++j) {
                float hj = __shfl(h, j, E_);
                gr = fmaf(hj, wr[j], gr);
                gz = fmaf(hj, wz[j], gz);
                hn = fmaf(hj, wn[j], hn);
            }
            float r = sigmoidf_(gr);
            float z = sigmoidf_(gz);
            float nn = tanhf_(fmaf(r, hn, gn));
            h = (1.0f - z) * nn + z * h;
            hsl[t][e] = h;
        }
    }
    __syncthreads();

    const int t = tid;
    float hrow[E_];
#pragma unroll
    for (int j = 0; j < E_; ++j) hrow[j] = hsl[t][j];

    float q[E_];
#pragma unroll
    for (int f = 0; f < E_; ++f) {
        float a = b_qkv[f];
#pragma unroll
        for (int j = 0; j < E_; ++j) a = fmaf(hrow[j], W_qkv[f * E_ + j], a);
        q[f] = a;
    }
#pragma unroll
    for (int f = 0; f < E_; ++f) {
        float a = b_qkv[E_ + f];
#pragma unroll
        for (int j = 0; j < E_; ++j) a = fmaf(hrow[j], W_qkv[(E_ + f) * E_ + j], a);
        ks[t][f] = a;
    }
#pragma unroll
    for (int f = 0; f < E_; ++f) {
        float a = b_qkv[2 * E_ + f];
#pragma unroll
        for (int j = 0; j < E_; ++j) a = fmaf(hrow[j], W_qkv[(2 * E_ + f) * E_ + j], a);
        vs[t][f] = a;
    }
    __syncthreads();

    const float scale = 0.70710678118654752f;   // 1/sqrt(D), D=2
    float l[4] = {0.f, 0.f, 0.f, 0.f};
    float acc[E_] = {0.f, 0.f, 0.f, 0.f, 0.f, 0.f, 0.f, 0.f};
    for (int s = 0; s < T_; ++s) {
        float4 k0 = *(const float4*)&ks[s][0];
        float4 k1 = *(const float4*)&ks[s][4];
        float4 v0 = *(const float4*)&vs[s][0];
        float4 v1 = *(const float4*)&vs[s][4];
        float p0 = __expf((q[0] * k0.x + q[1] * k0.y) * scale);
        float p1 = __expf((q[2] * k0.z + q[3] * k0.w) * scale);
        float p2 = __expf((q[4] * k1.x + q[5] * k1.y) * scale);
        float p3 = __expf((q[6] * k1.z + q[7] * k1.w) * scale);
        l[0] += p0; l[1] += p1; l[2] += p2; l[3] += p3;
        acc[0] = fmaf(p0, v0.x, acc[0]); acc[1] = fmaf(p0, v0.y, acc[1]);
        acc[2] = fmaf(p1, v0.z, acc[2]); acc[3] = fmaf(p1, v0.w, acc[3]);
        acc[4] = fmaf(p2, v1.x, acc[4]); acc[5] = fmaf(p2, v1.y, acc[5]);
        acc[6] = fmaf(p3, v1.z, acc[6]); acc[7] = fmaf(p3, v1.w, acc[7]);
    }

    // S = sum_f attn_out[t,f] = sum_e o[e] * (sum_f W_o[f,e]) + sum_f b_o[f]
    float S = 0.0f;
#pragma unroll
    for (int f = 0; f < E_; ++f) {
        float wsum = 0.0f;
#pragma unroll
        for (int fp = 0; fp < E_; ++fp) wsum += W_o[fp * E_ + f];
        S = fmaf(acc[f] / l[f >> 1], wsum, S);
    }
#pragma unroll
    for (int fp = 0; fp < E_; ++fp) S += b_o[fp];

    tsf_imp[(size_t)b * T_ * C_ + (size_t)t * C_ + c] = sigmoidf_(S);

    float* red = xcol;
    red[t] = S;
    __syncthreads();
    for (int off = 64; off > 0; off >>= 1) {
        if (t < off) red[t] += red[t + off];
        __syncthreads();
    }
    if (t == 0) feat_imp[bc] = sigmoidf_(red[0]);
}

// ---------------------------------------------------------------------------
// Kernel C: ts_imp (f32). grid = B*T, block = 64.
// ---------------------------------------------------------------------------
__global__ __launch_bounds__(64) void k_ts(
    const float* __restrict__ x,
    const float* __restrict__ W_ts1, const float* __restrict__ b_ts1,
    const float* __restrict__ W_ts2, const float* __restrict__ b_ts2,
    float* __restrict__ ts_imp)
{
    const int bt = blockIdx.x;
    const int tid = threadIdx.x;
    __shared__ float xs[C_];
    __shared__ float h1[16];
    xs[tid] = x[bt * C_ + tid];
    __syncthreads();
    if (tid < 16) {
        float a = b_ts1[tid];
#pragma unroll
        for (int k = 0; k < C_; ++k) a = fmaf(xs[k], W_ts1[tid * C_ + k], a);
        h1[tid] = 0.5f * a * (1.0f + erff(a * 0.70710678118654752f));
    }
    __syncthreads();
    if (tid == 0) {
        float s = b_ts2[0];
#pragma unroll
        for (int k = 0; k < 16; ++k) s = fmaf(h1[k], W_ts2[k], s);
        ts_imp[bt] = sigmoidf_(s);
    }
}

// ---------------------------------------------------------------------------
extern "C" void kernel_launch(void* const* d_in, const int* in_sizes, int n_in,
                              void* d_out, int out_size, void* d_ws, size_t ws_size,
                              hipStream_t stream) {
    (void)in_sizes; (void)n_in; (void)out_size; (void)d_ws; (void)ws_size;

    // OUTPUT IS FLOAT32 (reference computes in jnp.float32; "bf16" in the
    // test label is hardcoded text, not the buffer dtype).
    float* out0 = (float*)d_out;                 // (B, HID)    1024
    float* feat = out0 + B_ * HID_;              // (B, C)      2048
    float* tsim = feat + B_ * C_;                // (B, T)      4096
    float* tsf  = tsim + B_ * T_;                // (B, T, C) 262144

    const float* x     = (const float*)d_in[0];
    const float* W_in  = (const float*)d_in[1];
    const float* b_in  = (const float*)d_in[2];
    const float* W_ts1 = (const float*)d_in[3];
    const float* b_ts1 = (const float*)d_in[4];
    const float* W_ts2 = (const float*)d_in[5];
    const float* b_ts2 = (const float*)d_in[6];
    const float* W_ih  = (const float*)d_in[7];
    const float* W_hh  = (const float*)d_in[8];
    const float* b_ih  = (const float*)d_in[9];
    const float* b_hh  = (const float*)d_in[10];
    const float* W_qkv = (const float*)d_in[11];
    const float* b_qkv = (const float*)d_in[12];
    const float* W_o   = (const float*)d_in[13];
    const float* b_o   = (const float*)d_in[14];
    const float* W_out = (const float*)d_in[15];
    const float* b_out = (const float*)d_in[16];

    hipLaunchKernelGGL(k_gru_out, dim3(B_), dim3(512), 0, stream,
                       x, W_in, b_in, W_ih, W_hh, b_ih, b_hh, W_out, b_out, out0);
    hipLaunchKernelGGL(k_attn_f, dim3(B_ * C_), dim3(128), 0, stream,
                       x, W_in, b_in, W_ih, W_hh, b_ih, b_hh,
                       W_qkv, b_qkv, W_o, b_o, feat, tsf);
    hipLaunchKernelGGL(k_ts, dim3(B_ * T_), dim3(64), 0, stream,
                       x, W_ts1, b_ts1, W_ts2, b_ts2, tsim);
}

// Round 9
// 95.670 us; speedup vs baseline: 2.0187x; 2.0187x over previous
//
#include <hip/hip_runtime.h>
#include <hip/hip_bf16.h>
#include <math.h>

#define B_ 32
#define T_ 128
#define C_ 64
#define E_ 8
#define HID_ 32

__device__ __forceinline__ float sigmoidf_(float x) { return 1.0f / (1.0f + __expf(-x)); }
__device__ __forceinline__ float tanhf_(float x) {
    float xc = fminf(fmaxf(x, -15.0f), 15.0f);
    float e = __expf(2.0f * xc);
    return (e - 1.0f) / (e + 1.0f);
}

// ---------------------------------------------------------------------------
// Kernel B: per-chain xp + GRU + attention -> feat_imp, tsf_imp, fh (ws).
// grid = B*C, block = 128. The final hidden state feeds k_out via ws.
// ---------------------------------------------------------------------------
__global__ __launch_bounds__(128) void k_attn_f(
    const float* __restrict__ x, const float* __restrict__ W_in, const float* __restrict__ b_in,
    const float* __restrict__ W_ih, const float* __restrict__ W_hh,
    const float* __restrict__ b_ih, const float* __restrict__ b_hh,
    const float* __restrict__ W_qkv, const float* __restrict__ b_qkv,
    const float* __restrict__ W_o, const float* __restrict__ b_o,
    float* __restrict__ fh,
    float* __restrict__ feat_imp, float* __restrict__ tsf_imp)
{
    const int bc = blockIdx.x;
    const int b = bc >> 6, c = bc & 63;
    const int tid = threadIdx.x;

    __shared__ __align__(16) float ks[T_][E_];
    __shared__ __align__(16) float vs[T_][E_];
    __shared__ __align__(16) float hsl[T_][E_];
    __shared__ __align__(16) float xcol[T_];
    __shared__ __align__(16) float win_c[C_];

    if (tid < C_) win_c[tid] = W_in[c * C_ + tid];   // row c of W_in ('dc')
    __syncthreads();

    // xcol[t] = b_in[c] + x[b,t,:] . W_in[c,:]  (float4 x loads)
    {
        float a = b_in[c];
        const float4* xr = (const float4*)(x + (b * T_ + tid) * C_);
        const float4* wv4 = (const float4*)win_c;
#pragma unroll
        for (int k4 = 0; k4 < 16; ++k4) {
            float4 xv = xr[k4];
            float4 wv = wv4[k4];
            a = fmaf(xv.x, wv.x, a); a = fmaf(xv.y, wv.y, a);
            a = fmaf(xv.z, wv.z, a); a = fmaf(xv.w, wv.w, a);
        }
        xcol[tid] = a;
    }
    __syncthreads();

    // GRU on lanes 0..7 (one chain per block)
    if (tid < E_) {
        const int e = tid;
        float wr[E_], wz[E_], wn[E_];
#pragma unroll
        for (int j = 0; j < E_; ++j) {
            wr[j] = W_hh[(c * 24 + 0 * E_ + e) * E_ + j];
            wz[j] = W_hh[(c * 24 + 1 * E_ + e) * E_ + j];
            wn[j] = W_hh[(c * 24 + 2 * E_ + e) * E_ + j];
        }
        const float wir = W_ih[c * 24 + e], wiz = W_ih[c * 24 + E_ + e], win = W_ih[c * 24 + 2 * E_ + e];
        const float bir = b_ih[c * 24 + e], biz = b_ih[c * 24 + E_ + e], bin_ = b_ih[c * 24 + 2 * E_ + e];
        const float bhr = b_hh[c * 24 + e], bhz = b_hh[c * 24 + E_ + e], bhn = b_hh[c * 24 + 2 * E_ + e];

        float h = 0.0f;
        for (int t = 0; t < T_; ++t) {
            float xv = xcol[t];
            float gr = fmaf(xv, wir, bir) + bhr;
            float gz = fmaf(xv, wiz, biz) + bhz;
            float gn = fmaf(xv, win, bin_);
            float hn = bhn;
#pragma unroll
            for (int j = 0; j < E_; ++j) {
                float hj = __shfl(h, j, E_);
                gr = fmaf(hj, wr[j], gr);
                gz = fmaf(hj, wz[j], gz);
                hn = fmaf(hj, wn[j], hn);
            }
            float r = sigmoidf_(gr);
            float z = sigmoidf_(gz);
            float nn = tanhf_(fmaf(r, hn, gn));
            h = (1.0f - z) * nn + z * h;
            hsl[t][e] = h;
        }
        fh[bc * E_ + e] = h;          // final hidden state -> k_out
    }
    __syncthreads();

    // attention: thread t = time index
    const int t = tid;
    float hrow[E_];
#pragma unroll
    for (int j = 0; j < E_; ++j) hrow[j] = hsl[t][j];

    float q[E_];
#pragma unroll
    for (int f = 0; f < E_; ++f) {
        float a = b_qkv[f];
#pragma unroll
        for (int j = 0; j < E_; ++j) a = fmaf(hrow[j], W_qkv[f * E_ + j], a);
        q[f] = a;
    }
#pragma unroll
    for (int f = 0; f < E_; ++f) {
        float a = b_qkv[E_ + f];
#pragma unroll
        for (int j = 0; j < E_; ++j) a = fmaf(hrow[j], W_qkv[(E_ + f) * E_ + j], a);
        ks[t][f] = a;
    }
#pragma unroll
    for (int f = 0; f < E_; ++f) {
        float a = b_qkv[2 * E_ + f];
#pragma unroll
        for (int j = 0; j < E_; ++j) a = fmaf(hrow[j], W_qkv[(2 * E_ + f) * E_ + j], a);
        vs[t][f] = a;
    }
    __syncthreads();

    const float scale = 0.70710678118654752f;   // 1/sqrt(D), D=2
    float l[4] = {0.f, 0.f, 0.f, 0.f};
    float acc[E_] = {0.f, 0.f, 0.f, 0.f, 0.f, 0.f, 0.f, 0.f};
    for (int s = 0; s < T_; ++s) {
        float4 k0 = *(const float4*)&ks[s][0];
        float4 k1 = *(const float4*)&ks[s][4];
        float4 v0 = *(const float4*)&vs[s][0];
        float4 v1 = *(const float4*)&vs[s][4];
        float p0 = __expf((q[0] * k0.x + q[1] * k0.y) * scale);
        float p1 = __expf((q[2] * k0.z + q[3] * k0.w) * scale);
        float p2 = __expf((q[4] * k1.x + q[5] * k1.y) * scale);
        float p3 = __expf((q[6] * k1.z + q[7] * k1.w) * scale);
        l[0] += p0; l[1] += p1; l[2] += p2; l[3] += p3;
        acc[0] = fmaf(p0, v0.x, acc[0]); acc[1] = fmaf(p0, v0.y, acc[1]);
        acc[2] = fmaf(p1, v0.z, acc[2]); acc[3] = fmaf(p1, v0.w, acc[3]);
        acc[4] = fmaf(p2, v1.x, acc[4]); acc[5] = fmaf(p2, v1.y, acc[5]);
        acc[6] = fmaf(p3, v1.z, acc[6]); acc[7] = fmaf(p3, v1.w, acc[7]);
    }

    // S = sum over output features of attn_out[t,:]
    float S = 0.0f;
#pragma unroll
    for (int f = 0; f < E_; ++f) {
        float wsum = 0.0f;
#pragma unroll
        for (int fp = 0; fp < E_; ++fp) wsum += W_o[fp * E_ + f];
        S = fmaf(acc[f] / l[f >> 1], wsum, S);
    }
#pragma unroll
    for (int fp = 0; fp < E_; ++fp) S += b_o[fp];

    tsf_imp[(size_t)b * T_ * C_ + (size_t)t * C_ + c] = sigmoidf_(S);

    float* red = xcol;                 // phase-1 role dead
    red[t] = S;
    __syncthreads();
    for (int off = 64; off > 0; off >>= 1) {
        if (t < off) red[t] += red[t + off];
        __syncthreads();
    }
    if (t == 0) feat_imp[bc] = sigmoidf_(red[0]);
}

// ---------------------------------------------------------------------------
// Kernel C: ts_imp. grid = B*T, block = 64.
// ---------------------------------------------------------------------------
__global__ __launch_bounds__(64) void k_ts(
    const float* __restrict__ x,
    const float* __restrict__ W_ts1, const float* __restrict__ b_ts1,
    const float* __restrict__ W_ts2, const float* __restrict__ b_ts2,
    float* __restrict__ ts_imp)
{
    const int bt = blockIdx.x;
    const int tid = threadIdx.x;
    __shared__ float xs[C_];
    __shared__ float h1[16];
    xs[tid] = x[bt * C_ + tid];
    __syncthreads();
    if (tid < 16) {
        float a = b_ts1[tid];
#pragma unroll
        for (int k = 0; k < C_; ++k) a = fmaf(xs[k], W_ts1[tid * C_ + k], a);
        h1[tid] = 0.5f * a * (1.0f + erff(a * 0.70710678118654752f));
    }
    __syncthreads();
    if (tid == 0) {
        float s = b_ts2[0];
#pragma unroll
        for (int k = 0; k < 16; ++k) s = fmaf(h1[k], W_ts2[k], s);
        ts_imp[bt] = sigmoidf_(s);
    }
}

// ---------------------------------------------------------------------------
// Kernel D: out0[b,o] = b_out[o] + sum_{k} fh[b*C.. ][k] * W_out[o,k]
// grid = B, block = 64.
// ---------------------------------------------------------------------------
__global__ __launch_bounds__(64) void k_out(
    const float* __restrict__ fh, const float* __restrict__ W_out, const float* __restrict__ b_out,
    float* __restrict__ out0)
{
    const int b = blockIdx.x;
    const int tid = threadIdx.x;
    __shared__ float hf[C_ * E_];
    const float4* src = (const float4*)(fh + (b * C_ + tid) * E_);
    float4* dst = (float4*)(hf + tid * E_);
    dst[0] = src[0];
    dst[1] = src[1];
    __syncthreads();
    if (tid < HID_) {
        float a = b_out[tid];
        const float* wo = W_out + tid * (C_ * E_);
        for (int k = 0; k < C_ * E_; ++k) a = fmaf(hf[k], wo[k], a);
        out0[b * HID_ + tid] = a;
    }
}

// ---------------------------------------------------------------------------
extern "C" void kernel_launch(void* const* d_in, const int* in_sizes, int n_in,
                              void* d_out, int out_size, void* d_ws, size_t ws_size,
                              hipStream_t stream) {
    (void)in_sizes; (void)n_in; (void)out_size; (void)ws_size;

    // outputs are FLOAT32, concatenated in return order
    float* out0 = (float*)d_out;                 // (B, HID)    1024
    float* feat = out0 + B_ * HID_;              // (B, C)      2048
    float* tsim = feat + B_ * C_;                // (B, T)      4096
    float* tsf  = tsim + B_ * T_;                // (B, T, C) 262144

    const float* x     = (const float*)d_in[0];
    const float* W_in  = (const float*)d_in[1];
    const float* b_in  = (const float*)d_in[2];
    const float* W_ts1 = (const float*)d_in[3];
    const float* b_ts1 = (const float*)d_in[4];
    const float* W_ts2 = (const float*)d_in[5];
    const float* b_ts2 = (const float*)d_in[6];
    const float* W_ih  = (const float*)d_in[7];
    const float* W_hh  = (const float*)d_in[8];
    const float* b_ih  = (const float*)d_in[9];
    const float* b_hh  = (const float*)d_in[10];
    const float* W_qkv = (const float*)d_in[11];
    const float* b_qkv = (const float*)d_in[12];
    const float* W_o   = (const float*)d_in[13];
    const float* b_o   = (const float*)d_in[14];
    const float* W_out = (const float*)d_in[15];
    const float* b_out = (const float*)d_in[16];

    float* fhb = (float*)d_ws;                   // B*C*E f32 = 64 KB

    hipLaunchKernelGGL(k_attn_f, dim3(B_ * C_), dim3(128), 0, stream,
                       x, W_in, b_in, W_ih, W_hh, b_ih, b_hh,
                       W_qkv, b_qkv, W_o, b_o, fhb, feat, tsf);
    hipLaunchKernelGGL(k_ts, dim3(B_ * T_), dim3(64), 0, stream,
                       x, W_ts1, b_ts1, W_ts2, b_ts2, tsim);
    hipLaunchKernelGGL(k_out, dim3(B_), dim3(64), 0, stream,
                       fhb, W_out, b_out, out0);
}